// Round 1
// baseline (142.834 us; speedup 1.0000x reference)
//
#include <hip/hip_runtime.h>
#include <cfloat>

#define BS 64
#define C  1024
#define D  64
#define CT 128          // c rows per block
#define KT 128          // k rows per chunk
#define LDW (D + 4)     // padded LDS row stride (68 floats = 272 B, 16B-aligned)

__global__ __launch_bounds__(256, 2)
void triplet_main(const float* __restrict__ inputs,
                  const float* __restrict__ label,
                  const float* __restrict__ prot,
                  float* __restrict__ ws)
{
    __shared__ float xs[CT][LDW];
    __shared__ float ps[KT][LDW];
    __shared__ float xs2[CT];
    __shared__ float p2s[KT];
    __shared__ float snum[256];
    __shared__ float sden[256];

    const int tid = threadIdx.x;
    const int b   = blockIdx.x >> 3;
    const int c0  = (blockIdx.x & 7) * CT;

    // ---- stage X tile (128 x 64 fp32, rows contiguous in global) ----
    const float4* xg = (const float4*)(inputs + (size_t)(b * C + c0) * D);
    for (int idx = tid; idx < CT * (D / 4); idx += 256) {
        int r = idx >> 4, q = idx & 15;
        float4 v = xg[idx];
        *(float4*)&xs[r][q * 4] = v;
    }
    __syncthreads();

    // ---- normalize rows, compute x2 (post-normalization, like reference) ----
    if (tid < CT) {
        float s = 0.f;
        #pragma unroll
        for (int d = 0; d < D; d++) { float v = xs[tid][d]; s = fmaf(v, v, s); }
        float inv = 1.0f / fmaxf(sqrtf(s), 1e-12f);
        float s2 = 0.f;
        #pragma unroll
        for (int d = 0; d < D; d++) {
            float v = xs[tid][d] * inv;
            xs[tid][d] = v;
            s2 = fmaf(v, v, s2);
        }
        xs2[tid] = s2;
    }

    const int c_sub = tid & 15;   // 0..15
    const int k_sub = tid >> 4;   // 0..15

    float bestv[8];
    int   besti[8];
    #pragma unroll
    for (int i = 0; i < 8; i++) { bestv[i] = FLT_MAX; besti[i] = 0x7fffffff; }

    for (int kc = 0; kc < C / KT; kc++) {
        __syncthreads();  // prior readers of ps done; also covers normalize on iter 0
        // ---- stage prot chunk ----
        const float4* pg = (const float4*)(prot + (size_t)(kc * KT) * D);
        for (int idx = tid; idx < KT * (D / 4); idx += 256) {
            int r = idx >> 4, q = idx & 15;
            float4 v = pg[idx];
            *(float4*)&ps[r][q * 4] = v;
        }
        __syncthreads();
        if (tid < KT) {
            float s = 0.f;
            #pragma unroll
            for (int d = 0; d < D; d++) { float v = ps[tid][d]; s = fmaf(v, v, s); }
            p2s[tid] = s;
        }
        __syncthreads();

        // ---- 8x8 register-tiled dot products ----
        float acc[8][8];
        #pragma unroll
        for (int i = 0; i < 8; i++)
            #pragma unroll
            for (int j = 0; j < 8; j++) acc[i][j] = 0.f;

        for (int dd = 0; dd < D / 4; dd++) {
            float4 xv[8], pv[8];
            #pragma unroll
            for (int i = 0; i < 8; i++) xv[i] = *(const float4*)&xs[c_sub + 16 * i][dd * 4];
            #pragma unroll
            for (int j = 0; j < 8; j++) pv[j] = *(const float4*)&ps[k_sub + 16 * j][dd * 4];
            #pragma unroll
            for (int i = 0; i < 8; i++)
                #pragma unroll
                for (int j = 0; j < 8; j++) {
                    acc[i][j] = fmaf(xv[i].x, pv[j].x, acc[i][j]);
                    acc[i][j] = fmaf(xv[i].y, pv[j].y, acc[i][j]);
                    acc[i][j] = fmaf(xv[i].z, pv[j].z, acc[i][j]);
                    acc[i][j] = fmaf(xv[i].w, pv[j].w, acc[i][j]);
                }
        }

        // ---- fused running argmin over this k chunk ----
        #pragma unroll
        for (int i = 0; i < 8; i++) {
            const int   cg = c0 + c_sub + 16 * i;
            const float x2 = xs2[c_sub + 16 * i];
            #pragma unroll
            for (int j = 0; j < 8; j++) {
                const int kl = k_sub + 16 * j;
                const int kg = kc * KT + kl;
                float v = fmaxf(x2 + p2s[kl] - 2.0f * acc[i][j], 0.0f);
                // within a thread k strictly increases -> strict < keeps first index
                if (kg != cg && v < bestv[i]) { bestv[i] = v; besti[i] = kg; }
            }
        }
    }

    // ---- cross-thread argmin reduction (reuse ps as scratch) ----
    __syncthreads();
    float* redv = (float*)ps;
    int*   redi = (int*)((char*)ps + CT * 16 * sizeof(float));
    #pragma unroll
    for (int i = 0; i < 8; i++) {
        int c = c_sub + 16 * i;
        redv[c * 16 + k_sub] = bestv[i];
        redi[c * 16 + k_sub] = besti[i];
    }
    __syncthreads();

    float num = 0.f, den = 0.f;
    if (tid < CT) {
        const int c = tid;
        float bv = redv[c * 16];
        int   bi = redi[c * 16];
        #pragma unroll
        for (int s = 1; s < 16; s++) {
            float v = redv[c * 16 + s];
            int  ix = redi[c * 16 + s];
            if (v < bv || (v == bv && ix < bi)) { bv = v; bi = ix; }  // first-index tie-break
        }
        const int cg = c0 + c;
        const float4* pp = (const float4*)(prot + (size_t)cg * D);
        const float4* pn = (const float4*)(prot + (size_t)bi * D);
        float sap = 0.f, san = 0.f;
        #pragma unroll
        for (int q = 0; q < 16; q++) {
            float4 xv = *(const float4*)&xs[c][q * 4];
            float4 a  = pp[q];
            float4 nn = pn[q];
            float t;
            t = xv.x - a.x + 1e-6f;  sap = fmaf(t, t, sap);
            t = xv.y - a.y + 1e-6f;  sap = fmaf(t, t, sap);
            t = xv.z - a.z + 1e-6f;  sap = fmaf(t, t, sap);
            t = xv.w - a.w + 1e-6f;  sap = fmaf(t, t, sap);
            t = xv.x - nn.x + 1e-6f; san = fmaf(t, t, san);
            t = xv.y - nn.y + 1e-6f; san = fmaf(t, t, san);
            t = xv.z - nn.z + 1e-6f; san = fmaf(t, t, san);
            t = xv.w - nn.w + 1e-6f; san = fmaf(t, t, san);
        }
        float tri = fmaxf(sqrtf(sap) - sqrtf(san) + 0.2f, 0.0f);
        float w   = label[b * C + cg];
        num = tri * w;
        den = w;
    }

    snum[tid] = num;
    sden[tid] = den;
    __syncthreads();
    for (int s = 128; s > 0; s >>= 1) {
        if (tid < s) { snum[tid] += snum[tid + s]; sden[tid] += sden[tid + s]; }
        __syncthreads();
    }
    if (tid == 0) {
        atomicAdd(&ws[b * 2 + 0], snum[0]);
        atomicAdd(&ws[b * 2 + 1], sden[0]);
    }
}

__global__ void triplet_finish(const float* __restrict__ ws, float* __restrict__ out)
{
    int t = threadIdx.x;  // 64 threads = 1 wave
    float v = ws[t * 2] / ws[t * 2 + 1];
    #pragma unroll
    for (int off = 32; off > 0; off >>= 1) v += __shfl_down(v, off);
    if (t == 0) out[0] = v * (1.0f / (float)BS);
}

extern "C" void kernel_launch(void* const* d_in, const int* in_sizes, int n_in,
                              void* d_out, int out_size, void* d_ws, size_t ws_size,
                              hipStream_t stream)
{
    const float* inputs = (const float*)d_in[0];
    const float* label  = (const float*)d_in[1];
    const float* prot   = (const float*)d_in[2];
    float* out = (float*)d_out;
    float* ws  = (float*)d_ws;

    hipMemsetAsync(ws, 0, BS * 2 * sizeof(float), stream);
    triplet_main<<<dim3(BS * (C / CT)), dim3(256), 0, stream>>>(inputs, label, prot, ws);
    triplet_finish<<<1, 64, 0, stream>>>(ws, out);
}

// Round 2
// 51.649 us; speedup vs baseline: 2.7655x; 2.7655x over previous
//
#include <hip/hip_runtime.h>
#include <cfloat>

#define BS 64
#define C  1024
#define D  64
#define CT 128
#define KT 128
#define NCHUNK (C / KT)

typedef __attribute__((ext_vector_type(8))) short short8;
typedef __attribute__((ext_vector_type(4))) float f32x4;
typedef unsigned short ushort_t;
typedef unsigned int uint_t;

__device__ __forceinline__ ushort_t f2bf(float f) {
    uint_t u = __float_as_uint(f);
    u += 0x7fffu + ((u >> 16) & 1u);          // round-to-nearest-even
    return (ushort_t)(u >> 16);
}
__device__ __forceinline__ float bf2f(ushort_t h) {
    return __uint_as_float(((uint_t)h) << 16);
}

// ---- prep: split prototypes into frag-ordered bf16 hi/lo + p2 ----
__global__ void prep_prot(const float* __restrict__ prot,
                          ushort_t* __restrict__ ph, ushort_t* __restrict__ pl,
                          float* __restrict__ p2)
{
    const int k = blockIdx.x * 128 + threadIdx.x;   // 0..1023
    const float4* row = (const float4*)(prot + (size_t)k * D);
    const int kc = k >> 7;          // chunk
    const int j  = (k & 127) >> 4;  // col-tile within chunk
    float s = 0.f;
    #pragma unroll
    for (int dg = 0; dg < 8; dg++) {
        float4 a = row[dg * 2];
        float4 b = row[dg * 2 + 1];
        float x[8] = {a.x, a.y, a.z, a.w, b.x, b.y, b.z, b.w};
        short8 hv, lv;
        #pragma unroll
        for (int e = 0; e < 8; e++) {
            s = fmaf(x[e], x[e], s);
            ushort_t hb = f2bf(x[e]);
            hv[e] = (short)hb;
            lv[e] = (short)f2bf(x[e] - bf2f(hb));
        }
        const int h  = dg >> 2;
        const int ln = (k & 15) + (dg & 3) * 16;
        const int f  = j * 2 + h;
        const size_t idx = (size_t)kc * 1024 + f * 64 + ln;   // short8 units
        ((short8*)ph)[idx] = hv;
        ((short8*)pl)[idx] = lv;
    }
    p2[k] = s;
}

// ---- main: fused MFMA scores + argmin + triplet epilogue ----
__global__ __launch_bounds__(256, 2)
void triplet_mfma(const float* __restrict__ inputs,
                  const float* __restrict__ label,
                  const float* __restrict__ prot,
                  const ushort_t* __restrict__ phg,
                  const ushort_t* __restrict__ plg,
                  const float* __restrict__ p2g,
                  float* __restrict__ part)
{
    __shared__ short8 xh[1024], xl[1024];     // X frags, 16 KB each
    __shared__ short8 phs[1024], pls[1024];   // P chunk frags, 16 KB each
    __shared__ float  p2s[KT];
    __shared__ float  invn[CT];
    __shared__ float  redv[CT * 2];
    __shared__ int    redi[CT * 2];
    __shared__ float  snum[256], sden[256];

    const int tid  = threadIdx.x;
    const int lane = tid & 63;
    const int wid  = tid >> 6;
    const int wr   = wid >> 1;     // wave row (0..1) -> 64 c-rows
    const int wc   = wid & 1;      // wave col (0..1) -> 64 k-cols per chunk
    const int b    = blockIdx.x >> 3;
    const int c0   = (blockIdx.x & 7) * CT;

    // phase 1: per-row inverse norms
    if (tid < CT) {
        const float4* r = (const float4*)(inputs + (size_t)(b * C + c0 + tid) * D);
        float s = 0.f;
        #pragma unroll
        for (int q = 0; q < 16; q++) {
            float4 v = r[q];
            s = fmaf(v.x, v.x, fmaf(v.y, v.y, fmaf(v.z, v.z, fmaf(v.w, v.w, s))));
        }
        invn[tid] = 1.0f / fmaxf(sqrtf(s), 1e-12f);
    }
    __syncthreads();

    // phase 2: normalize + split X into frag-ordered hi/lo bf16
    #pragma unroll
    for (int it = 0; it < 4; it++) {
        int task = tid + it * 256;            // 0..1023
        int r = task >> 3, dg = task & 7;
        const float* src = inputs + (size_t)(b * C + c0 + r) * D + dg * 8;
        float inv = invn[r];
        float4 a = *(const float4*)src;
        float4 bb = *(const float4*)(src + 4);
        float x[8] = {a.x, a.y, a.z, a.w, bb.x, bb.y, bb.z, bb.w};
        short8 hv, lv;
        #pragma unroll
        for (int e = 0; e < 8; e++) {
            float xv = x[e] * inv;
            ushort_t hb = f2bf(xv);
            hv[e] = (short)hb;
            lv[e] = (short)f2bf(xv - bf2f(hb));
        }
        int f  = (r >> 4) * 2 + (dg >> 2);
        int ln = (r & 15) + (dg & 3) * 16;
        xh[f * 64 + ln] = hv;
        xl[f * 64 + ln] = lv;
    }
    __syncthreads();

    // A fragments for this wave's 64 rows (held in registers for all chunks)
    short8 ah[4][2], al[4][2];
    #pragma unroll
    for (int i = 0; i < 4; i++)
        #pragma unroll
        for (int h = 0; h < 2; h++) {
            int f = (4 * wr + i) * 2 + h;
            ah[i][h] = xh[f * 64 + lane];
            al[i][h] = xl[f * 64 + lane];
        }

    float bestv[4][4];
    int   besti[4][4];
    #pragma unroll
    for (int i = 0; i < 4; i++)
        #pragma unroll
        for (int r = 0; r < 4; r++) { bestv[i][r] = FLT_MAX; besti[i][r] = 0; }

    for (int kc = 0; kc < NCHUNK; kc++) {
        __syncthreads();   // prior readers of phs/pls done
        {
            const short8* sh = (const short8*)phg + (size_t)kc * 1024;
            const short8* sl = (const short8*)plg + (size_t)kc * 1024;
            #pragma unroll
            for (int it = 0; it < 4; it++) {
                phs[tid + it * 256] = sh[tid + it * 256];
                pls[tid + it * 256] = sl[tid + it * 256];
            }
            if (tid < KT) p2s[tid] = p2g[kc * KT + tid];
        }
        __syncthreads();

        #pragma unroll
        for (int j = 0; j < 4; j++) {
            const int jj = wc * 4 + j;
            short8 bh0 = phs[(jj * 2 + 0) * 64 + lane];
            short8 bh1 = phs[(jj * 2 + 1) * 64 + lane];
            short8 bl0 = pls[(jj * 2 + 0) * 64 + lane];
            short8 bl1 = pls[(jj * 2 + 1) * 64 + lane];
            const int   colg = kc * KT + jj * 16 + (lane & 15);
            const float p2v  = p2s[jj * 16 + (lane & 15)];
            #pragma unroll
            for (int i = 0; i < 4; i++) {
                f32x4 acc = {0.f, 0.f, 0.f, 0.f};
                acc = __builtin_amdgcn_mfma_f32_16x16x32_bf16(ah[i][0], bh0, acc, 0, 0, 0);
                acc = __builtin_amdgcn_mfma_f32_16x16x32_bf16(ah[i][1], bh1, acc, 0, 0, 0);
                acc = __builtin_amdgcn_mfma_f32_16x16x32_bf16(ah[i][0], bl0, acc, 0, 0, 0);
                acc = __builtin_amdgcn_mfma_f32_16x16x32_bf16(ah[i][1], bl1, acc, 0, 0, 0);
                acc = __builtin_amdgcn_mfma_f32_16x16x32_bf16(al[i][0], bh0, acc, 0, 0, 0);
                acc = __builtin_amdgcn_mfma_f32_16x16x32_bf16(al[i][1], bh1, acc, 0, 0, 0);
                const bool dtile = (c0 + wr * 64 + i * 16) == (kc * KT + jj * 16);
                const int  rsub  = (lane >> 4) * 4;
                #pragma unroll
                for (int r = 0; r < 4; r++) {
                    float v = fmaf(acc[r], -2.0f, p2v);   // p2 - 2S (argmin-equiv to d2)
                    if (dtile && (rsub + r) == (lane & 15)) v = FLT_MAX;  // mask diagonal
                    if (v < bestv[i][r]) { bestv[i][r] = v; besti[i][r] = colg; }
                }
            }
        }
    }

    // cross-lane argmin over the 16 col-lanes (first-index tie-break)
    #pragma unroll
    for (int i = 0; i < 4; i++)
        #pragma unroll
        for (int r = 0; r < 4; r++) {
            float v = bestv[i][r]; int ix = besti[i][r];
            #pragma unroll
            for (int off = 1; off < 16; off <<= 1) {
                float ov = __shfl_xor(v, off);
                int   oi = __shfl_xor(ix, off);
                if (ov < v || (ov == v && oi < ix)) { v = ov; ix = oi; }
            }
            if ((lane & 15) == 0) {
                int rowl = wr * 64 + i * 16 + (lane >> 4) * 4 + r;
                redv[rowl * 2 + wc] = v;
                redi[rowl * 2 + wc] = ix;
            }
        }
    __syncthreads();

    // final per-row epilogue: d_ap / d_an in fp32, triplet loss
    float num = 0.f, den = 0.f;
    if (tid < CT) {
        float v0 = redv[tid * 2],     v1 = redv[tid * 2 + 1];
        int   i0 = redi[tid * 2],     i1 = redi[tid * 2 + 1];
        int   bi = (v1 < v0 || (v1 == v0 && i1 < i0)) ? i1 : i0;
        const int cg = c0 + tid;
        const float inv = invn[tid];
        const float4* xr = (const float4*)(inputs + (size_t)(b * C + cg) * D);
        const float4* pp = (const float4*)(prot + (size_t)cg * D);
        const float4* pn = (const float4*)(prot + (size_t)bi * D);
        float sap = 0.f, san = 0.f;
        #pragma unroll
        for (int q = 0; q < 16; q++) {
            float4 xv = xr[q];
            float4 aa = pp[q];
            float4 nn = pn[q];
            float t;
            t = fmaf(xv.x, inv, -aa.x) + 1e-6f;  sap = fmaf(t, t, sap);
            t = fmaf(xv.y, inv, -aa.y) + 1e-6f;  sap = fmaf(t, t, sap);
            t = fmaf(xv.z, inv, -aa.z) + 1e-6f;  sap = fmaf(t, t, sap);
            t = fmaf(xv.w, inv, -aa.w) + 1e-6f;  sap = fmaf(t, t, sap);
            t = fmaf(xv.x, inv, -nn.x) + 1e-6f;  san = fmaf(t, t, san);
            t = fmaf(xv.y, inv, -nn.y) + 1e-6f;  san = fmaf(t, t, san);
            t = fmaf(xv.z, inv, -nn.z) + 1e-6f;  san = fmaf(t, t, san);
            t = fmaf(xv.w, inv, -nn.w) + 1e-6f;  san = fmaf(t, t, san);
        }
        float tri = fmaxf(sqrtf(sap) - sqrtf(san) + 0.2f, 0.0f);
        float w   = label[b * C + cg];
        num = tri * w;
        den = w;
    }

    snum[tid] = num;
    sden[tid] = den;
    __syncthreads();
    for (int s = 128; s > 0; s >>= 1) {
        if (tid < s) { snum[tid] += snum[tid + s]; sden[tid] += sden[tid + s]; }
        __syncthreads();
    }
    if (tid == 0) {
        atomicAdd(&part[b * 2 + 0], snum[0]);
        atomicAdd(&part[b * 2 + 1], sden[0]);
    }
}

__global__ void triplet_finish(const float* __restrict__ part, float* __restrict__ out)
{
    int t = threadIdx.x;  // 64 threads = 1 wave
    float v = part[t * 2] / part[t * 2 + 1];
    #pragma unroll
    for (int off = 32; off > 0; off >>= 1) v += __shfl_down(v, off);
    if (t == 0) out[0] = v * (1.0f / (float)BS);
}

extern "C" void kernel_launch(void* const* d_in, const int* in_sizes, int n_in,
                              void* d_out, int out_size, void* d_ws, size_t ws_size,
                              hipStream_t stream)
{
    const float* inputs = (const float*)d_in[0];
    const float* label  = (const float*)d_in[1];
    const float* prot   = (const float*)d_in[2];
    float* out = (float*)d_out;

    ushort_t* phg = (ushort_t*)d_ws;            // 128 KB
    ushort_t* plg = phg + (size_t)C * D;        // 128 KB
    float*    p2g = (float*)(plg + (size_t)C * D);  // 4 KB
    float*    part = p2g + C;                   // 512 B

    hipMemsetAsync(part, 0, BS * 2 * sizeof(float), stream);
    prep_prot<<<dim3(C / 128), dim3(128), 0, stream>>>(prot, phg, plg, p2g);
    triplet_mfma<<<dim3(BS * (C / CT)), dim3(256), 0, stream>>>(
        inputs, label, prot, phg, plg, p2g, part);
    triplet_finish<<<1, 64, 0, stream>>>(part, out);
}

// Round 3
// 45.549 us; speedup vs baseline: 3.1358x; 1.1339x over previous
//
#include <hip/hip_runtime.h>
#include <cfloat>

#define BS 64
#define C  1024
#define D  64
#define CT 128

typedef __attribute__((ext_vector_type(8))) short short8;
typedef __attribute__((ext_vector_type(4))) float f32x4;
typedef unsigned short ushort_t;
typedef unsigned int uint_t;

__device__ __forceinline__ ushort_t f2bf(float f) {
    uint_t u = __float_as_uint(f);
    u += 0x7fffu + ((u >> 16) & 1u);          // round-to-nearest-even
    return (ushort_t)(u >> 16);
}
__device__ __forceinline__ float bf2f(ushort_t h) {
    return __uint_as_float(((uint_t)h) << 16);
}

// ---- prep: split prototypes into frag-ordered bf16 hi/lo + p2 ----
// layout (short8 units): idx = jt*128 + h*64 + ln, jt = k>>4 (col tile),
// h = K-half, ln = (k&15) + kslot*16  -> one wave's load of 64 lanes is
// 1KB contiguous per fragment.
__global__ void prep_prot(const float* __restrict__ prot,
                          ushort_t* __restrict__ ph, ushort_t* __restrict__ pl,
                          float* __restrict__ p2)
{
    const int k = blockIdx.x * 128 + threadIdx.x;   // 0..1023
    const float4* row = (const float4*)(prot + (size_t)k * D);
    const int jt = k >> 4;
    float s = 0.f;
    #pragma unroll
    for (int dg = 0; dg < 8; dg++) {
        float4 a = row[dg * 2];
        float4 b = row[dg * 2 + 1];
        float x[8] = {a.x, a.y, a.z, a.w, b.x, b.y, b.z, b.w};
        short8 hv, lv;
        #pragma unroll
        for (int e = 0; e < 8; e++) {
            s = fmaf(x[e], x[e], s);
            ushort_t hb = f2bf(x[e]);
            hv[e] = (short)hb;
            lv[e] = (short)f2bf(x[e] - bf2f(hb));
        }
        const int h  = dg >> 2;
        const int ln = (k & 15) + (dg & 3) * 16;
        const size_t idx = (size_t)jt * 128 + h * 64 + ln;   // short8 units
        ((short8*)ph)[idx] = hv;
        ((short8*)pl)[idx] = lv;
    }
    p2[k] = s;
}

// ---- main: barrier-free MFMA k-loop, B frags streamed from L2 ----
__global__ __launch_bounds__(256, 2)
void triplet_mfma(const float* __restrict__ inputs,
                  const float* __restrict__ label,
                  const float* __restrict__ prot,
                  const ushort_t* __restrict__ phg,
                  const ushort_t* __restrict__ plg,
                  const float* __restrict__ p2g,
                  float* __restrict__ part)
{
    __shared__ short8 xh[1024], xl[1024];     // X frags, 16 KB each
    __shared__ float  p2s[C];                 // 4 KB, staged once
    __shared__ float  invn[CT];
    __shared__ float  redv[CT * 2];
    __shared__ int    redi[CT * 2];
    __shared__ float  snum[256], sden[256];

    const int tid  = threadIdx.x;
    const int lane = tid & 63;
    const int wid  = tid >> 6;
    const int wr   = wid >> 1;     // wave row (0..1) -> 64 c-rows
    const int wc   = wid & 1;      // wave col (0..1) -> 512 k-cols
    const int b    = blockIdx.x >> 3;
    const int c0   = (blockIdx.x & 7) * CT;

    // stage p2 (once) + per-row inverse norms
    ((float4*)p2s)[tid] = ((const float4*)p2g)[tid];
    if (tid < CT) {
        const float4* r = (const float4*)(inputs + (size_t)(b * C + c0 + tid) * D);
        float s = 0.f;
        #pragma unroll
        for (int q = 0; q < 16; q++) {
            float4 v = r[q];
            s = fmaf(v.x, v.x, fmaf(v.y, v.y, fmaf(v.z, v.z, fmaf(v.w, v.w, s))));
        }
        invn[tid] = 1.0f / fmaxf(sqrtf(s), 1e-12f);
    }
    __syncthreads();

    // normalize + split X into frag-ordered hi/lo bf16
    #pragma unroll
    for (int it = 0; it < 4; it++) {
        int task = tid + it * 256;            // 0..1023
        int r = task >> 3, dg = task & 7;
        const float* src = inputs + (size_t)(b * C + c0 + r) * D + dg * 8;
        float inv = invn[r];
        float4 a = *(const float4*)src;
        float4 bb = *(const float4*)(src + 4);
        float x[8] = {a.x, a.y, a.z, a.w, bb.x, bb.y, bb.z, bb.w};
        short8 hv, lv;
        #pragma unroll
        for (int e = 0; e < 8; e++) {
            float xv = x[e] * inv;
            ushort_t hb = f2bf(xv);
            hv[e] = (short)hb;
            lv[e] = (short)f2bf(xv - bf2f(hb));
        }
        int f  = (r >> 4) * 2 + (dg >> 2);
        int ln = (r & 15) + (dg & 3) * 16;
        xh[f * 64 + ln] = hv;
        xl[f * 64 + ln] = lv;
    }
    __syncthreads();

    // A fragments for this wave's 64 rows (registers, all iterations)
    short8 ah[4][2], al[4][2];
    #pragma unroll
    for (int i = 0; i < 4; i++)
        #pragma unroll
        for (int h = 0; h < 2; h++) {
            int f = (4 * wr + i) * 2 + h;
            ah[i][h] = xh[f * 64 + lane];
            al[i][h] = xl[f * 64 + lane];
        }

    float bestv[4][4];
    int   besti[4][4];
    #pragma unroll
    for (int i = 0; i < 4; i++)
        #pragma unroll
        for (int r = 0; r < 4; r++) { bestv[i][r] = FLT_MAX; besti[i][r] = 0; }

    // barrier-free k-loop: 32 col-tiles per wave, 1-deep B prefetch from L2
    const short8* BH = (const short8*)phg;
    const short8* BL = (const short8*)plg;
    int jg = wc * 32;
    short8 cb0 = BH[jg * 128 + lane];
    short8 cb1 = BH[jg * 128 + 64 + lane];
    short8 cb2 = BL[jg * 128 + lane];
    short8 cb3 = BL[jg * 128 + 64 + lane];

    for (int jt = 0; jt < 32; jt++, jg++) {
        const int jn = (jt == 31) ? jg : (jg + 1);
        short8 nb0 = BH[jn * 128 + lane];
        short8 nb1 = BH[jn * 128 + 64 + lane];
        short8 nb2 = BL[jn * 128 + lane];
        short8 nb3 = BL[jn * 128 + 64 + lane];

        const float p2v  = p2s[jg * 16 + (lane & 15)];
        const int   colg = jg * 16 + (lane & 15);
        const int   rsub = (lane >> 4) * 4;

        #pragma unroll
        for (int i = 0; i < 4; i++) {
            f32x4 acc = {0.f, 0.f, 0.f, 0.f};
            acc = __builtin_amdgcn_mfma_f32_16x16x32_bf16(ah[i][0], cb0, acc, 0, 0, 0);
            acc = __builtin_amdgcn_mfma_f32_16x16x32_bf16(ah[i][1], cb1, acc, 0, 0, 0);
            acc = __builtin_amdgcn_mfma_f32_16x16x32_bf16(ah[i][0], cb2, acc, 0, 0, 0);
            acc = __builtin_amdgcn_mfma_f32_16x16x32_bf16(ah[i][1], cb3, acc, 0, 0, 0);
            acc = __builtin_amdgcn_mfma_f32_16x16x32_bf16(al[i][0], cb0, acc, 0, 0, 0);
            acc = __builtin_amdgcn_mfma_f32_16x16x32_bf16(al[i][1], cb1, acc, 0, 0, 0);
            const bool dtile = (c0 + wr * 64 + i * 16) == jg * 16;
            #pragma unroll
            for (int r = 0; r < 4; r++) {
                float v = fmaf(acc[r], -2.0f, p2v);   // p2 - 2S (argmin-equiv to d2)
                if (dtile && (rsub + r) == (lane & 15)) v = FLT_MAX;
                if (v < bestv[i][r]) { bestv[i][r] = v; besti[i][r] = colg; }
            }
        }
        cb0 = nb0; cb1 = nb1; cb2 = nb2; cb3 = nb3;
    }

    // cross-lane argmin over the 16 col-lanes (first-index tie-break)
    #pragma unroll
    for (int i = 0; i < 4; i++)
        #pragma unroll
        for (int r = 0; r < 4; r++) {
            float v = bestv[i][r]; int ix = besti[i][r];
            #pragma unroll
            for (int off = 1; off < 16; off <<= 1) {
                float ov = __shfl_xor(v, off);
                int   oi = __shfl_xor(ix, off);
                if (ov < v || (ov == v && oi < ix)) { v = ov; ix = oi; }
            }
            if ((lane & 15) == 0) {
                int rowl = wr * 64 + i * 16 + (lane >> 4) * 4 + r;
                redv[rowl * 2 + wc] = v;
                redi[rowl * 2 + wc] = ix;
            }
        }
    __syncthreads();

    // final per-row epilogue: d_ap / d_an in fp32, triplet loss
    float num = 0.f, den = 0.f;
    if (tid < CT) {
        float v0 = redv[tid * 2],     v1 = redv[tid * 2 + 1];
        int   i0 = redi[tid * 2],     i1 = redi[tid * 2 + 1];
        int   bi = (v1 < v0 || (v1 == v0 && i1 < i0)) ? i1 : i0;
        const int cg = c0 + tid;
        const float inv = invn[tid];
        const float4* xr = (const float4*)(inputs + (size_t)(b * C + cg) * D);
        const float4* pp = (const float4*)(prot + (size_t)cg * D);
        const float4* pn = (const float4*)(prot + (size_t)bi * D);
        float sap = 0.f, san = 0.f;
        #pragma unroll
        for (int q = 0; q < 16; q++) {
            float4 xv = xr[q];
            float4 aa = pp[q];
            float4 nn = pn[q];
            float t;
            t = fmaf(xv.x, inv, -aa.x) + 1e-6f;  sap = fmaf(t, t, sap);
            t = fmaf(xv.y, inv, -aa.y) + 1e-6f;  sap = fmaf(t, t, sap);
            t = fmaf(xv.z, inv, -aa.z) + 1e-6f;  sap = fmaf(t, t, sap);
            t = fmaf(xv.w, inv, -aa.w) + 1e-6f;  sap = fmaf(t, t, sap);
            t = fmaf(xv.x, inv, -nn.x) + 1e-6f;  san = fmaf(t, t, san);
            t = fmaf(xv.y, inv, -nn.y) + 1e-6f;  san = fmaf(t, t, san);
            t = fmaf(xv.z, inv, -nn.z) + 1e-6f;  san = fmaf(t, t, san);
            t = fmaf(xv.w, inv, -nn.w) + 1e-6f;  san = fmaf(t, t, san);
        }
        float tri = fmaxf(sqrtf(sap) - sqrtf(san) + 0.2f, 0.0f);
        float w   = label[b * C + cg];
        num = tri * w;
        den = w;
    }

    snum[tid] = num;
    sden[tid] = den;
    __syncthreads();
    for (int s = 128; s > 0; s >>= 1) {
        if (tid < s) { snum[tid] += snum[tid + s]; sden[tid] += sden[tid + s]; }
        __syncthreads();
    }
    if (tid == 0) {
        part[blockIdx.x * 2 + 0] = snum[0];
        part[blockIdx.x * 2 + 1] = sden[0];
    }
}

__global__ void triplet_finish(const float* __restrict__ part, float* __restrict__ out)
{
    int t = threadIdx.x;  // 64 threads = 1 wave; t = batch index
    float num = 0.f, den = 0.f;
    #pragma unroll
    for (int h = 0; h < 8; h++) {
        num += part[(t * 8 + h) * 2 + 0];
        den += part[(t * 8 + h) * 2 + 1];
    }
    float v = num / den;
    #pragma unroll
    for (int off = 32; off > 0; off >>= 1) v += __shfl_down(v, off);
    if (t == 0) out[0] = v * (1.0f / (float)BS);
}

extern "C" void kernel_launch(void* const* d_in, const int* in_sizes, int n_in,
                              void* d_out, int out_size, void* d_ws, size_t ws_size,
                              hipStream_t stream)
{
    const float* inputs = (const float*)d_in[0];
    const float* label  = (const float*)d_in[1];
    const float* prot   = (const float*)d_in[2];
    float* out = (float*)d_out;

    ushort_t* phg = (ushort_t*)d_ws;                 // 128 KB
    ushort_t* plg = phg + (size_t)C * D;             // 128 KB
    float*    p2g = (float*)(plg + (size_t)C * D);   // 4 KB
    float*    part = p2g + C;                        // 4 KB (512 x 2)

    prep_prot<<<dim3(C / 128), dim3(128), 0, stream>>>(prot, phg, plg, p2g);
    triplet_mfma<<<dim3(BS * (C / CT)), dim3(256), 0, stream>>>(
        inputs, label, prot, phg, plg, p2g, part);
    triplet_finish<<<1, 64, 0, stream>>>(part, out);
}

// Round 4
// 32.081 us; speedup vs baseline: 4.4523x; 1.4198x over previous
//
#include <hip/hip_runtime.h>
#include <cfloat>

#define BS 64
#define C  1024
#define D  64
#define CT 128

typedef __attribute__((ext_vector_type(8))) short short8;
typedef __attribute__((ext_vector_type(4))) float f32x4;
typedef unsigned short ushort_t;
typedef unsigned int uint_t;

__device__ __forceinline__ ushort_t f2bf(float f) {
    uint_t u = __float_as_uint(f);
    u += 0x7fffu + ((u >> 16) & 1u);          // round-to-nearest-even
    return (ushort_t)(u >> 16);
}

// ---- prep: bf16(hi) prototypes, frag-ordered ----
// short8 idx = jt*128 + h*64 + ln;  jt=k>>4, h=K-half, ln=(k&15)+kslot*16
__global__ void prep_prot(const float* __restrict__ prot, ushort_t* __restrict__ ph)
{
    const int k = blockIdx.x * 128 + threadIdx.x;   // 0..1023
    const float4* row = (const float4*)(prot + (size_t)k * D);
    const int jt = k >> 4;
    #pragma unroll
    for (int dg = 0; dg < 8; dg++) {
        float4 a = row[dg * 2];
        float4 b = row[dg * 2 + 1];
        float x[8] = {a.x, a.y, a.z, a.w, b.x, b.y, b.z, b.w};
        short8 hv;
        #pragma unroll
        for (int e = 0; e < 8; e++) hv[e] = (short)f2bf(x[e]);
        const int h  = dg >> 2;
        const int ln = (k & 15) + (dg & 3) * 16;
        ((short8*)ph)[(size_t)jt * 128 + h * 64 + ln] = hv;
    }
}

// ---- main: 8-wave block, single-pass MFMA, packed-key argmax(S) ----
__global__ __launch_bounds__(512, 4)
void triplet_mfma(const float* __restrict__ inputs,
                  const float* __restrict__ label,
                  const float* __restrict__ prot,
                  const ushort_t* __restrict__ phg,
                  float* __restrict__ part)
{
    __shared__ short8 xh[1024];          // 16 KB X hi-frags
    __shared__ float  invn[CT];
    __shared__ uint_t redk[CT][4];
    __shared__ float  snum[512], sden[512];

    const int tid  = threadIdx.x;
    const int lane = tid & 63;
    const int wid  = tid >> 6;     // 0..7
    const int wr   = wid >> 2;     // 0..1 -> 64 c-rows
    const int wc   = wid & 3;      // 0..3 -> 256 k-cols
    const int b    = blockIdx.x >> 3;
    const int c0   = (blockIdx.x & 7) * CT;

    const short8* BH = (const short8*)phg;

    // issue first two B tiles immediately (covered by staging phase)
    short8 ta0 = BH[(size_t)(wc * 16 + 0) * 128 + lane];
    short8 ta1 = BH[(size_t)(wc * 16 + 0) * 128 + 64 + lane];
    short8 tb0 = BH[(size_t)(wc * 16 + 1) * 128 + lane];
    short8 tb1 = BH[(size_t)(wc * 16 + 1) * 128 + 64 + lane];

    // per-row inverse norms
    if (tid < CT) {
        const float4* r = (const float4*)(inputs + (size_t)(b * C + c0 + tid) * D);
        float s = 0.f;
        #pragma unroll
        for (int q = 0; q < 16; q++) {
            float4 v = r[q];
            s = fmaf(v.x, v.x, fmaf(v.y, v.y, fmaf(v.z, v.z, fmaf(v.w, v.w, s))));
        }
        invn[tid] = 1.0f / fmaxf(sqrtf(s), 1e-12f);
    }
    __syncthreads();

    // normalize + split X into frag-ordered hi bf16
    #pragma unroll
    for (int it = 0; it < 2; it++) {
        int task = tid + it * 512;            // 0..1023
        int r = task >> 3, dg = task & 7;
        const float* src = inputs + (size_t)(b * C + c0 + r) * D + dg * 8;
        float inv = invn[r];
        float4 a = *(const float4*)src;
        float4 bb = *(const float4*)(src + 4);
        float x[8] = {a.x, a.y, a.z, a.w, bb.x, bb.y, bb.z, bb.w};
        short8 hv;
        #pragma unroll
        for (int e = 0; e < 8; e++) hv[e] = (short)f2bf(x[e] * inv);
        int f  = (r >> 4) * 2 + (dg >> 2);
        int ln = (r & 15) + (dg & 3) * 16;
        xh[f * 64 + ln] = hv;
    }
    __syncthreads();

    // A fragments for this wave's 64 rows
    short8 ah[4][2];
    #pragma unroll
    for (int i = 0; i < 4; i++) {
        ah[i][0] = xh[((4 * wr + i) * 2 + 0) * 64 + lane];
        ah[i][1] = xh[((4 * wr + i) * 2 + 1) * 64 + lane];
    }

    uint_t bestk[16];
    #pragma unroll
    for (int q = 0; q < 16; q++) bestk[q] = 0u;

    const uint_t MMASK = 0xFFFFFC00u;
    const int rowtile0 = (c0 >> 4) + wr * 4;
    const int rsub = (lane >> 4) * 4;
    const int csub = lane & 15;

    auto process = [&](int jt, short8 b0, short8 b1) {
        const int jg = wc * 16 + jt;
        const uint_t cidx = (uint_t)(1023 - (jg * 16 + csub));
        #pragma unroll
        for (int i = 0; i < 4; i++) {
            f32x4 acc = {2.0f, 2.0f, 2.0f, 2.0f};      // S + 2 > 0 -> sortable bits
            acc = __builtin_amdgcn_mfma_f32_16x16x32_bf16(ah[i][0], b0, acc, 0, 0, 0);
            acc = __builtin_amdgcn_mfma_f32_16x16x32_bf16(ah[i][1], b1, acc, 0, 0, 0);
            const bool dtile = (rowtile0 + i) == jg;   // wave-uniform
            #pragma unroll
            for (int r = 0; r < 4; r++) {
                uint_t key = (__float_as_uint(acc[r]) & MMASK) | cidx;
                if (dtile && (rsub + r) == csub) key = 0u;   // mask diagonal
                bestk[i * 4 + r] = bestk[i * 4 + r] > key ? bestk[i * 4 + r] : key;
            }
        }
    };

    // 16 tiles per wave, 2-tile-deep register prefetch, no barriers
    for (int jt = 0; jt < 16; jt += 2) {
        const int p0 = (jt + 2 < 16) ? jt + 2 : 15;
        const int p1 = (jt + 3 < 16) ? jt + 3 : 15;
        short8 n0 = BH[(size_t)(wc * 16 + p0) * 128 + lane];
        short8 n1 = BH[(size_t)(wc * 16 + p0) * 128 + 64 + lane];
        process(jt, ta0, ta1);
        short8 m0 = BH[(size_t)(wc * 16 + p1) * 128 + lane];
        short8 m1 = BH[(size_t)(wc * 16 + p1) * 128 + 64 + lane];
        process(jt + 1, tb0, tb1);
        ta0 = n0; ta1 = n1; tb0 = m0; tb1 = m1;
    }

    // cross-lane max over the 16 col-lanes
    #pragma unroll
    for (int i = 0; i < 4; i++)
        #pragma unroll
        for (int r = 0; r < 4; r++) {
            uint_t v = bestk[i * 4 + r];
            #pragma unroll
            for (int off = 1; off < 16; off <<= 1) {
                uint_t ov = (uint_t)__shfl_xor((int)v, off);
                v = v > ov ? v : ov;
            }
            if (csub == 0)
                redk[wr * 64 + i * 16 + rsub + r][wc] = v;
        }
    __syncthreads();

    // per-row epilogue: exact fp32 d_ap / d_an, triplet loss
    float num = 0.f, den = 0.f;
    if (tid < CT) {
        uint_t k0 = redk[tid][0], k1 = redk[tid][1];
        uint_t k2 = redk[tid][2], k3 = redk[tid][3];
        uint_t kk = k0 > k1 ? k0 : k1;
        uint_t kl = k2 > k3 ? k2 : k3;
        kk = kk > kl ? kk : kl;
        const int bi = 1023 - (int)(kk & 0x3FFu);
        const int cg = c0 + tid;
        const float inv = invn[tid];
        const float4* xr = (const float4*)(inputs + (size_t)(b * C + cg) * D);
        const float4* pp = (const float4*)(prot + (size_t)cg * D);
        const float4* pn = (const float4*)(prot + (size_t)bi * D);
        float sap = 0.f, san = 0.f;
        #pragma unroll
        for (int q = 0; q < 16; q++) {
            float4 xv = xr[q];
            float4 aa = pp[q];
            float4 nn = pn[q];
            float t;
            t = fmaf(xv.x, inv, -aa.x) + 1e-6f;  sap = fmaf(t, t, sap);
            t = fmaf(xv.y, inv, -aa.y) + 1e-6f;  sap = fmaf(t, t, sap);
            t = fmaf(xv.z, inv, -aa.z) + 1e-6f;  sap = fmaf(t, t, sap);
            t = fmaf(xv.w, inv, -aa.w) + 1e-6f;  sap = fmaf(t, t, sap);
            t = fmaf(xv.x, inv, -nn.x) + 1e-6f;  san = fmaf(t, t, san);
            t = fmaf(xv.y, inv, -nn.y) + 1e-6f;  san = fmaf(t, t, san);
            t = fmaf(xv.z, inv, -nn.z) + 1e-6f;  san = fmaf(t, t, san);
            t = fmaf(xv.w, inv, -nn.w) + 1e-6f;  san = fmaf(t, t, san);
        }
        float tri = fmaxf(sqrtf(sap) - sqrtf(san) + 0.2f, 0.0f);
        float w   = label[b * C + cg];
        num = tri * w;
        den = w;
    }

    snum[tid] = num;
    sden[tid] = den;
    __syncthreads();
    for (int s = 256; s > 0; s >>= 1) {
        if (tid < s) { snum[tid] += snum[tid + s]; sden[tid] += sden[tid + s]; }
        __syncthreads();
    }
    if (tid == 0) {
        part[blockIdx.x * 2 + 0] = snum[0];
        part[blockIdx.x * 2 + 1] = sden[0];
    }
}

__global__ void triplet_finish(const float* __restrict__ part, float* __restrict__ out)
{
    int t = threadIdx.x;  // 64 threads = 1 wave; t = batch index
    float num = 0.f, den = 0.f;
    #pragma unroll
    for (int h = 0; h < 8; h++) {
        num += part[(t * 8 + h) * 2 + 0];
        den += part[(t * 8 + h) * 2 + 1];
    }
    float v = num / den;
    #pragma unroll
    for (int off = 32; off > 0; off >>= 1) v += __shfl_down(v, off);
    if (t == 0) out[0] = v * (1.0f / (float)BS);
}

extern "C" void kernel_launch(void* const* d_in, const int* in_sizes, int n_in,
                              void* d_out, int out_size, void* d_ws, size_t ws_size,
                              hipStream_t stream)
{
    const float* inputs = (const float*)d_in[0];
    const float* label  = (const float*)d_in[1];
    const float* prot   = (const float*)d_in[2];
    float* out = (float*)d_out;

    ushort_t* phg  = (ushort_t*)d_ws;                // 128 KB
    float*    part = (float*)(phg + (size_t)C * D);  // 4 KB (512 x 2)

    prep_prot<<<dim3(C / 128), dim3(128), 0, stream>>>(prot, phg);
    triplet_mfma<<<dim3(BS * (C / CT)), dim3(512), 0, stream>>>(
        inputs, label, prot, phg, part);
    triplet_finish<<<1, 64, 0, stream>>>(part, out);
}